// Round 1
// baseline (419.227 us; speedup 1.0000x reference)
//
#include <hip/hip_runtime.h>
#include <hip/hip_bf16.h>
#include <cstdio>
#include <cstdint>

// Attention (B=4, S=2048, D=1024, full-dim, fp32 I/O) via bf16 MFMA GEMMs.
// Pipeline: cvt(x,W*) -> Q,K,V GEMMs -> transpose(V) -> scores GEMM (fp32)
//           -> row softmax (P bf16) -> PV GEMM -> output GEMM (fp32 out).

typedef __attribute__((ext_vector_type(8))) short short8;
typedef __attribute__((ext_vector_type(4))) float f32x4;

#define AS1(p) ((const __attribute__((address_space(1))) void*)(p))
#define AS3(p) ((__attribute__((address_space(3))) void*)(p))

__device__ __forceinline__ unsigned short f2bf(float f) {
  union { float f; uint32_t u; } c; c.f = f;
  uint32_t u = c.u + 0x7fffu + ((c.u >> 16) & 1u);  // RNE (no NaN inputs here)
  return (unsigned short)(u >> 16);
}

// ---------------- fp32 -> bf16 convert (float4 -> ushort4) ----------------
__global__ void cvt_f32_bf16(const float* __restrict__ in,
                             unsigned short* __restrict__ out, int n4) {
  int i = blockIdx.x * 256 + threadIdx.x;
  if (i >= n4) return;
  float4 v = ((const float4*)in)[i];
  ushort4 o;
  o.x = f2bf(v.x); o.y = f2bf(v.y); o.z = f2bf(v.z); o.w = f2bf(v.w);
  ((ushort4*)out)[i] = o;
}

// ---------------- bf16 [2048][1024] -> [1024][2048] transpose (per batch) --
__global__ void transpose_bf16(const unsigned short* __restrict__ V,
                               unsigned short* __restrict__ Vt) {
  __shared__ unsigned short tile[64][72];  // +8 pad breaks bank conflicts
  const int b = blockIdx.z;
  const unsigned short* v = V + (size_t)b * 2048 * 1024;
  unsigned short* vt = Vt + (size_t)b * 1024 * 2048;
  const int d0 = blockIdx.x * 64, s0 = blockIdx.y * 64;
  const int t = threadIdx.x;
#pragma unroll
  for (int it = 0; it < 16; ++it) {
    int idx = it * 256 + t, r = idx >> 6, c = idx & 63;
    tile[r][c] = v[(size_t)(s0 + r) * 1024 + d0 + c];
  }
  __syncthreads();
#pragma unroll
  for (int it = 0; it < 16; ++it) {
    int idx = it * 256 + t, r = idx >> 6, c = idx & 63;
    vt[(size_t)(d0 + r) * 2048 + s0 + c] = tile[c][r];
  }
}

// ---------------- row softmax: fp32 [rows][2048] -> bf16 P -----------------
__global__ void softmax_rows(const float* __restrict__ S,
                             unsigned short* __restrict__ P) {
  const size_t row = blockIdx.x;
  const float* s = S + row * 2048;
  const int t = threadIdx.x, l = t & 63, w = t >> 6;
  float4 v0 = ((const float4*)s)[t * 2];
  float4 v1 = ((const float4*)s)[t * 2 + 1];
  float x[8] = {v0.x, v0.y, v0.z, v0.w, v1.x, v1.y, v1.z, v1.w};
  float m = x[0];
#pragma unroll
  for (int j = 1; j < 8; ++j) m = fmaxf(m, x[j]);
#pragma unroll
  for (int d = 32; d; d >>= 1) m = fmaxf(m, __shfl_xor(m, d));
  __shared__ float rm[4], rs[4];
  if (l == 0) rm[w] = m;
  __syncthreads();
  m = fmaxf(fmaxf(rm[0], rm[1]), fmaxf(rm[2], rm[3]));
  float e[8], sum = 0.f;
#pragma unroll
  for (int j = 0; j < 8; ++j) { e[j] = __expf(x[j] - m); sum += e[j]; }
#pragma unroll
  for (int d = 32; d; d >>= 1) sum += __shfl_xor(sum, d);
  if (l == 0) rs[w] = sum;
  __syncthreads();
  float inv = 1.0f / (rs[0] + rs[1] + rs[2] + rs[3]);
  short8 o;
#pragma unroll
  for (int j = 0; j < 8; ++j) o[j] = (short)f2bf(e[j] * inv);
  *(short8*)(P + row * 2048 + t * 8) = o;
}

// ---------------- bf16 GEMM, C = scale * A @ B^T ---------------------------
// A: [M][lda] bf16, B: [N][ldb] bf16 (row n holds column n of the math-B).
// 128x128 block tile, BK=32, 4 waves (2x2 of 64x64), mfma_f32_16x16x32_bf16.
// LDS is fragment-linear: 16-B slot s of m-block mb holds
// A[mb*16 + (s&15)][kt*32 + (s>>4)*8 .. +8] so ds_read is base + lane*16
// (conflict-free) and global_load_lds's linear-dest constraint is satisfied
// by permuting the per-lane *global* source address instead.
__device__ __forceinline__ void store_out(float* p, float v) { *p = v; }
__device__ __forceinline__ void store_out(unsigned short* p, float v) { *p = f2bf(v); }

template <typename OutT>
__global__ __launch_bounds__(256, 2) void gemm_bt(
    const unsigned short* __restrict__ A, const unsigned short* __restrict__ B,
    OutT* __restrict__ C, int lda, int ldb, int ldc, int kIters,
    long long aStride, long long bStride, long long cStride, float scale) {
  __shared__ unsigned short ldsA[4096];  // 8 KB: 8 m-blocks x 64 slots x 16 B
  __shared__ unsigned short ldsB[4096];
  const int t = threadIdx.x, l = t & 63, w = t >> 6;
  const int wr = w >> 1, wc = w & 1;
  const int r0 = blockIdx.y * 128, c0 = blockIdx.x * 128;
  A += (size_t)blockIdx.z * aStride;
  B += (size_t)blockIdx.z * bStride;
  C += (size_t)blockIdx.z * cStride;

  // per-lane global sources: wave w stages m-blocks {w, 4+w}
  const unsigned short* aP = A + (size_t)(r0 + w * 16 + (l & 15)) * lda + (l >> 4) * 8;
  const unsigned short* bP = B + (size_t)(c0 + w * 16 + (l & 15)) * ldb + (l >> 4) * 8;
  const size_t a64 = (size_t)64 * lda, b64 = (size_t)64 * ldb;
  unsigned short* dA1 = &ldsA[w * 512];         // wave-uniform LDS dests
  unsigned short* dA2 = &ldsA[2048 + w * 512];
  unsigned short* dB1 = &ldsB[w * 512];
  unsigned short* dB2 = &ldsB[2048 + w * 512];

  f32x4 acc[4][4] = {};

  for (int kt = 0; kt < kIters; ++kt) {
    __builtin_amdgcn_global_load_lds(AS1(aP),       AS3(dA1), 16, 0, 0);
    __builtin_amdgcn_global_load_lds(AS1(aP + a64), AS3(dA2), 16, 0, 0);
    __builtin_amdgcn_global_load_lds(AS1(bP),       AS3(dB1), 16, 0, 0);
    __builtin_amdgcn_global_load_lds(AS1(bP + b64), AS3(dB2), 16, 0, 0);
    aP += 32; bP += 32;
    __syncthreads();  // drains vmcnt -> staged tile visible
    short8 af[4], bfv[4];
#pragma unroll
    for (int m = 0; m < 4; ++m)
      af[m] = *(const short8*)&ldsA[(wr * 4 + m) * 512 + l * 8];
#pragma unroll
    for (int n = 0; n < 4; ++n)
      bfv[n] = *(const short8*)&ldsB[(wc * 4 + n) * 512 + l * 8];
#pragma unroll
    for (int m = 0; m < 4; ++m)
#pragma unroll
      for (int n = 0; n < 4; ++n)
        acc[m][n] = __builtin_amdgcn_mfma_f32_16x16x32_bf16(af[m], bfv[n], acc[m][n], 0, 0, 0);
    __syncthreads();  // LDS reads done before next stage overwrites
  }

  // C/D layout (m89-verified): col = lane&15, row = (lane>>4)*4 + i
  const int cr = (l >> 4) * 4, cc = l & 15;
#pragma unroll
  for (int m = 0; m < 4; ++m)
#pragma unroll
    for (int n = 0; n < 4; ++n) {
      int col = c0 + wc * 64 + n * 16 + cc;
#pragma unroll
      for (int i = 0; i < 4; ++i) {
        int row = r0 + wr * 64 + m * 16 + cr + i;
        store_out(&C[(size_t)row * ldc + col], acc[m][n][i] * scale);
      }
    }
}

// ---------------- workspace layout (bytes, all 256-aligned) ----------------
static const size_t OFF_XB  = 0;            // x bf16        16,777,216
static const size_t OFF_WQ  = 16777216;     // wq bf16        2,097,152
static const size_t OFF_WK  = 18874368;
static const size_t OFF_WV  = 20971520;
static const size_t OFF_WO  = 23068672;
static const size_t OFF_Q   = 25165824;     // Q bf16        16,777,216
static const size_t OFF_K   = 41943040;
static const size_t OFF_V   = 58720256;
static const size_t OFF_VT  = 75497472;     // V^T bf16      16,777,216
static const size_t OFF_SC  = 92274688;     // scores fp32   67,108,864
static const size_t OFF_P   = 159383552;    // P bf16        33,554,432
static const size_t OFF_CTX = 192937984;    // ctx bf16      16,777,216
static const size_t WS_NEED = 209715200;    // 200 MiB

extern "C" void kernel_launch(void* const* d_in, const int* in_sizes, int n_in,
                              void* d_out, int out_size, void* d_ws, size_t ws_size,
                              hipStream_t stream) {
  const float* x  = (const float*)d_in[0];
  const float* wq = (const float*)d_in[1];
  const float* wk = (const float*)d_in[2];
  const float* wv = (const float*)d_in[3];
  const float* wo = (const float*)d_in[4];
  float* out = (float*)d_out;

  if (ws_size < WS_NEED) {
    fprintf(stderr, "kernel_launch: ws_size=%zu < needed %zu\n", ws_size, WS_NEED);
    return;
  }
  char* ws = (char*)d_ws;
  unsigned short* xb  = (unsigned short*)(ws + OFF_XB);
  unsigned short* wqb = (unsigned short*)(ws + OFF_WQ);
  unsigned short* wkb = (unsigned short*)(ws + OFF_WK);
  unsigned short* wvb = (unsigned short*)(ws + OFF_WV);
  unsigned short* wob = (unsigned short*)(ws + OFF_WO);
  unsigned short* Qb  = (unsigned short*)(ws + OFF_Q);
  unsigned short* Kb  = (unsigned short*)(ws + OFF_K);
  unsigned short* Vb  = (unsigned short*)(ws + OFF_V);
  unsigned short* Vt  = (unsigned short*)(ws + OFF_VT);
  float*          Sc  = (float*)(ws + OFF_SC);
  unsigned short* Pb  = (unsigned short*)(ws + OFF_P);
  unsigned short* Cx  = (unsigned short*)(ws + OFF_CTX);

  // 1) convert inputs to bf16
  cvt_f32_bf16<<<8192, 256, 0, stream>>>(x,  xb,  2097152);
  cvt_f32_bf16<<<1024, 256, 0, stream>>>(wq, wqb, 262144);
  cvt_f32_bf16<<<1024, 256, 0, stream>>>(wk, wkb, 262144);
  cvt_f32_bf16<<<1024, 256, 0, stream>>>(wv, wvb, 262144);
  cvt_f32_bf16<<<1024, 256, 0, stream>>>(wo, wob, 262144);

  // 2) Q/K/V = x @ W^T   (M=8192, N=1024, K=1024)
  gemm_bt<unsigned short><<<dim3(8, 64, 1), 256, 0, stream>>>(
      xb, wqb, Qb, 1024, 1024, 1024, 32, 0, 0, 0, 1.0f);
  gemm_bt<unsigned short><<<dim3(8, 64, 1), 256, 0, stream>>>(
      xb, wkb, Kb, 1024, 1024, 1024, 32, 0, 0, 0, 1.0f);
  gemm_bt<unsigned short><<<dim3(8, 64, 1), 256, 0, stream>>>(
      xb, wvb, Vb, 1024, 1024, 1024, 32, 0, 0, 0, 1.0f);

  // 3) V^T per batch
  transpose_bf16<<<dim3(16, 32, 4), 256, 0, stream>>>(Vb, Vt);

  // 4) scores = Q @ K^T / 32   (per batch, M=N=2048, K=1024, fp32 out)
  gemm_bt<float><<<dim3(16, 16, 4), 256, 0, stream>>>(
      Qb, Kb, Sc, 1024, 1024, 2048, 32,
      2097152LL, 2097152LL, 4194304LL, 0.03125f);

  // 5) P = softmax(scores) -> bf16
  softmax_rows<<<8192, 256, 0, stream>>>(Sc, Pb);

  // 6) ctx = P @ V  (= P @ (V^T)^T; per batch, M=2048, N=1024, K=2048)
  gemm_bt<unsigned short><<<dim3(8, 16, 4), 256, 0, stream>>>(
      Pb, Vt, Cx, 2048, 2048, 1024, 64,
      4194304LL, 2097152LL, 2097152LL, 1.0f);

  // 7) out = ctx @ wo^T  (M=8192, N=1024, K=1024, fp32 out)
  gemm_bt<float><<<dim3(8, 64, 1), 256, 0, stream>>>(
      Cx, wob, out, 1024, 1024, 1024, 32, 0, 0, 0, 1.0f);
}

// Round 2
// 376.806 us; speedup vs baseline: 1.1126x; 1.1126x over previous
//
#include <hip/hip_runtime.h>
#include <hip/hip_bf16.h>
#include <cstdio>
#include <cstdint>

// Attention (B=4, S=2048, D=1024, full-dim, fp32 I/O) via bf16 MFMA GEMMs.
// Round 2: pipelined GEMM — BK=32, 4 LDS buffers, prefetch distance 2,
// counted vmcnt (never 0 in main loop), ONE raw s_barrier per K-tile,
// 8 waves/block, 2 blocks/CU, bijective XCD swizzle, fused QKV.

typedef __attribute__((ext_vector_type(8))) short short8;
typedef __attribute__((ext_vector_type(4))) float f32x4;

#define AS1(p) ((const __attribute__((address_space(1))) void*)(p))
#define AS3(p) ((__attribute__((address_space(3))) void*)(p))

__device__ __forceinline__ unsigned short f2bf(float f) {
  union { float f; uint32_t u; } c; c.f = f;
  uint32_t u = c.u + 0x7fffu + ((c.u >> 16) & 1u);  // RNE (no NaN inputs here)
  return (unsigned short)(u >> 16);
}

// ---------------- fp32 -> bf16 convert (float4 -> ushort4) ----------------
__global__ void cvt_f32_bf16(const float* __restrict__ in,
                             unsigned short* __restrict__ out, int n4) {
  int i = blockIdx.x * 256 + threadIdx.x;
  if (i >= n4) return;
  float4 v = ((const float4*)in)[i];
  ushort4 o;
  o.x = f2bf(v.x); o.y = f2bf(v.y); o.z = f2bf(v.z); o.w = f2bf(v.w);
  ((ushort4*)out)[i] = o;
}

// all 4 weight matrices in one launch (each 1,048,576 elems, out contiguous)
__global__ void cvt_w4(const float* __restrict__ a, const float* __restrict__ b,
                       const float* __restrict__ c, const float* __restrict__ d,
                       unsigned short* __restrict__ out) {
  const float* s = (blockIdx.y == 0) ? a : (blockIdx.y == 1) ? b
                 : (blockIdx.y == 2) ? c : d;
  int i = blockIdx.x * 256 + threadIdx.x;
  float4 v = ((const float4*)s)[i];
  ushort4 o;
  o.x = f2bf(v.x); o.y = f2bf(v.y); o.z = f2bf(v.z); o.w = f2bf(v.w);
  ((ushort4*)(out + (size_t)blockIdx.y * 1048576))[i] = o;
}

// ---------------- bf16 [2048][1024] -> [1024][2048] transpose (per batch) --
__global__ void transpose_bf16(const unsigned short* __restrict__ V,
                               unsigned short* __restrict__ Vt) {
  __shared__ unsigned short tile[64][72];
  const int b = blockIdx.z;
  const unsigned short* v = V + (size_t)b * 2048 * 1024;
  unsigned short* vt = Vt + (size_t)b * 1024 * 2048;
  const int d0 = blockIdx.x * 64, s0 = blockIdx.y * 64;
  const int t = threadIdx.x;
#pragma unroll
  for (int it = 0; it < 16; ++it) {
    int idx = it * 256 + t, r = idx >> 6, c = idx & 63;
    tile[r][c] = v[(size_t)(s0 + r) * 1024 + d0 + c];
  }
  __syncthreads();
#pragma unroll
  for (int it = 0; it < 16; ++it) {
    int idx = it * 256 + t, r = idx >> 6, c = idx & 63;
    vt[(size_t)(d0 + r) * 2048 + s0 + c] = tile[c][r];
  }
}

// ---------------- row softmax: fp32 [rows][2048] -> bf16 P -----------------
__global__ void softmax_rows(const float* __restrict__ S,
                             unsigned short* __restrict__ P) {
  const size_t row = blockIdx.x;
  const float* s = S + row * 2048;
  const int t = threadIdx.x, l = t & 63, w = t >> 6;
  float4 v0 = ((const float4*)s)[t * 2];
  float4 v1 = ((const float4*)s)[t * 2 + 1];
  float x[8] = {v0.x, v0.y, v0.z, v0.w, v1.x, v1.y, v1.z, v1.w};
  float m = x[0];
#pragma unroll
  for (int j = 1; j < 8; ++j) m = fmaxf(m, x[j]);
#pragma unroll
  for (int d = 32; d; d >>= 1) m = fmaxf(m, __shfl_xor(m, d));
  __shared__ float rm[4], rs[4];
  if (l == 0) rm[w] = m;
  __syncthreads();
  m = fmaxf(fmaxf(rm[0], rm[1]), fmaxf(rm[2], rm[3]));
  float e[8], sum = 0.f;
#pragma unroll
  for (int j = 0; j < 8; ++j) { e[j] = __expf(x[j] - m); sum += e[j]; }
#pragma unroll
  for (int d = 32; d; d >>= 1) sum += __shfl_xor(sum, d);
  if (l == 0) rs[w] = sum;
  __syncthreads();
  float inv = 1.0f / (rs[0] + rs[1] + rs[2] + rs[3]);
  short8 o;
#pragma unroll
  for (int j = 0; j < 8; ++j) o[j] = (short)f2bf(e[j] * inv);
  *(short8*)(P + row * 2048 + t * 8) = o;
}

// ---------------- pipelined bf16 GEMM, C = scale * A @ B^T -----------------
// 128x128 block tile, BK=32, 8 waves (4M x 2N, wave tile 32x64), NBUF=4
// K-tile LDS buffers (16 KB each = 64 KB). Iter kt stages tile kt+2 into
// buf[(kt+2)&3] (wave-uniform dest; fragment permutation applied on the
// per-lane GLOBAL source address), waits vmcnt(4) (2 tiles stay in flight),
// one raw s_barrier, then ds_read_b128 frags + 8 MFMA.
// Race proof: writes to buf[j&3] for tile j+4 are issued post-barrier_{j+2};
// reads of tile j were consumed (lgkmcnt before MFMA) pre-barrier_{j+1}.
__device__ __forceinline__ void store_out(float* p, float v) { *p = v; }
__device__ __forceinline__ void store_out(unsigned short* p, float v) { *p = f2bf(v); }

template <typename OutT>
__global__ __launch_bounds__(512, 4) void gemm_bt(
    const unsigned short* __restrict__ A, const unsigned short* __restrict__ B,
    OutT* __restrict__ C, int lda, int ldb, int ldc, int nk,
    long long aStride, long long bStride, long long cStride, float scale) {
  __shared__ unsigned short lds[32768];  // 64 KB = 4 bufs x (A 8KB + B 8KB)
  const int t = threadIdx.x, l = t & 63, w = t >> 6;
  const int wr = w >> 1, wc = w & 1;

  // bijective XCD-aware block swizzle (all our grids have nwg % 8 == 0)
  const int gx = gridDim.x, gy = gridDim.y;
  int f = blockIdx.x + gx * (blockIdx.y + gy * blockIdx.z);
  int nwg = gx * gy * gridDim.z;
  int work = ((nwg & 7) == 0) ? ((f & 7) * (nwg >> 3) + (f >> 3)) : f;
  const int bx = work % gx;
  int rem = work / gx;
  const int by = rem % gy, bz = rem / gy;
  const int r0 = by * 128, col0 = bx * 128;
  A += (size_t)bz * aStride;
  B += (size_t)bz * bStride;
  C += (size_t)bz * cStride;

  // staging: 16 chunks of 1 KB per K-tile (A mb 0..7, B nb 0..7); wave w owns
  // chunks {2w, 2w+1}. Chunk c, lane l <- src row (origin + c*16 + (l&15)),
  // cols (l>>4)*8..+8 of the K-tile.
  const unsigned short* sp[2];
  int dstoff[2];
#pragma unroll
  for (int j = 0; j < 2; ++j) {
    int c = 2 * w + j;
    bool isA = c < 8;
    int row = (isA ? r0 + c * 16 : col0 + (c - 8) * 16) + (l & 15);
    sp[j] = (isA ? A : B) + (size_t)row * (isA ? lda : ldb) + (l >> 4) * 8;
    dstoff[j] = c * 1024;  // byte offset within a buffer (A: 0..8K, B: 8K..16K)
  }

#define STAGE(kt_, b_)                                                        \
  do {                                                                        \
    _Pragma("unroll") for (int j = 0; j < 2; ++j)                             \
        __builtin_amdgcn_global_load_lds(AS1(sp[j] + (size_t)(kt_) * 32),     \
                                         AS3((char*)lds + (b_) * 16384 + dstoff[j]), \
                                         16, 0, 0);                           \
  } while (0)

  f32x4 acc[2][4] = {};
  STAGE(0, 0);
  if (nk > 1) STAGE(1, 1);

  for (int kt = 0; kt < nk; ++kt) {
    if (kt + 2 < nk) {
      STAGE(kt + 2, (kt + 2) & 3);
      asm volatile("s_waitcnt vmcnt(4)" ::: "memory");  // tile kt drained, 2 in flight
    } else if (kt + 1 < nk) {
      asm volatile("s_waitcnt vmcnt(2)" ::: "memory");
    } else {
      asm volatile("s_waitcnt vmcnt(0)" ::: "memory");
    }
    __builtin_amdgcn_s_barrier();
    asm volatile("" ::: "memory");

    const int bb = (kt & 3) * 8192;  // buffer base in shorts
    short8 af[2], bfv[4];
#pragma unroll
    for (int m = 0; m < 2; ++m)
      af[m] = *(const short8*)&lds[bb + ((wr * 2 + m) * 64 + l) * 8];
#pragma unroll
    for (int n = 0; n < 4; ++n)
      bfv[n] = *(const short8*)&lds[bb + 4096 + ((wc * 4 + n) * 64 + l) * 8];
#pragma unroll
    for (int m = 0; m < 2; ++m)
#pragma unroll
      for (int n = 0; n < 4; ++n)
        acc[m][n] = __builtin_amdgcn_mfma_f32_16x16x32_bf16(af[m], bfv[n], acc[m][n], 0, 0, 0);
  }
#undef STAGE

  // C/D layout: col = lane&15, row = (lane>>4)*4 + i  (round-1 verified)
  const int cr = (l >> 4) * 4, cc = l & 15;
#pragma unroll
  for (int m = 0; m < 2; ++m)
#pragma unroll
    for (int n = 0; n < 4; ++n) {
      int col = col0 + wc * 64 + n * 16 + cc;
#pragma unroll
      for (int i = 0; i < 4; ++i) {
        int row = r0 + wr * 32 + m * 16 + cr + i;
        store_out(&C[(size_t)row * ldc + col], acc[m][n][i] * scale);
      }
    }
}

// ---------------- workspace layout (bytes, all 256-aligned) ----------------
static const size_t OFF_XB  = 0;            // x bf16        16,777,216
static const size_t OFF_WQ  = 16777216;     // wq bf16        2,097,152
static const size_t OFF_WK  = 18874368;
static const size_t OFF_WV  = 20971520;
static const size_t OFF_WO  = 23068672;
static const size_t OFF_Q   = 25165824;     // Q bf16        16,777,216
static const size_t OFF_K   = 41943040;
static const size_t OFF_V   = 58720256;
static const size_t OFF_VT  = 75497472;     // V^T bf16      16,777,216
static const size_t OFF_SC  = 92274688;     // scores fp32   67,108,864
static const size_t OFF_P   = 159383552;    // P bf16        33,554,432
static const size_t OFF_CTX = 192937984;    // ctx bf16      16,777,216
static const size_t WS_NEED = 209715200;    // 200 MiB

extern "C" void kernel_launch(void* const* d_in, const int* in_sizes, int n_in,
                              void* d_out, int out_size, void* d_ws, size_t ws_size,
                              hipStream_t stream) {
  const float* x  = (const float*)d_in[0];
  const float* wq = (const float*)d_in[1];
  const float* wk = (const float*)d_in[2];
  const float* wv = (const float*)d_in[3];
  const float* wo = (const float*)d_in[4];
  float* out = (float*)d_out;

  if (ws_size < WS_NEED) {
    fprintf(stderr, "kernel_launch: ws_size=%zu < needed %zu\n", ws_size, WS_NEED);
    return;
  }
  char* ws = (char*)d_ws;
  unsigned short* xb  = (unsigned short*)(ws + OFF_XB);
  unsigned short* wqb = (unsigned short*)(ws + OFF_WQ);
  unsigned short* Qb  = (unsigned short*)(ws + OFF_Q);
  unsigned short* Kb  = (unsigned short*)(ws + OFF_K);
  unsigned short* Vb  = (unsigned short*)(ws + OFF_V);
  unsigned short* Vt  = (unsigned short*)(ws + OFF_VT);
  float*          Sc  = (float*)(ws + OFF_SC);
  unsigned short* Pb  = (unsigned short*)(ws + OFF_P);
  unsigned short* Cx  = (unsigned short*)(ws + OFF_CTX);
  unsigned short* wob = (unsigned short*)(ws + OFF_WO);

  // 1) convert inputs to bf16 (weights land contiguous at OFF_WQ..OFF_WO)
  cvt_f32_bf16<<<8192, 256, 0, stream>>>(x, xb, 2097152);
  cvt_w4<<<dim3(1024, 4, 1), 256, 0, stream>>>(wq, wk, wv, wo, wqb);

  // 2) fused QKV: z selects weight (bStride) and output (cStride)
  //    M=8192, N=1024, K=1024; Q,K,V land contiguous at OFF_Q/K/V
  gemm_bt<unsigned short><<<dim3(8, 64, 3), 512, 0, stream>>>(
      xb, wqb, Qb, 1024, 1024, 1024, 32, 0, 1048576LL, 8388608LL, 1.0f);

  // 3) V^T per batch
  transpose_bf16<<<dim3(16, 32, 4), 256, 0, stream>>>(Vb, Vt);

  // 4) scores = Q @ K^T / 32   (per batch, M=N=2048, K=1024, fp32 out)
  gemm_bt<float><<<dim3(16, 16, 4), 512, 0, stream>>>(
      Qb, Kb, Sc, 1024, 1024, 2048, 32,
      2097152LL, 2097152LL, 4194304LL, 0.03125f);

  // 5) P = softmax(scores) -> bf16
  softmax_rows<<<8192, 256, 0, stream>>>(Sc, Pb);

  // 6) ctx = P @ V  (per batch, M=2048, N=1024, K=2048)
  gemm_bt<unsigned short><<<dim3(8, 16, 4), 512, 0, stream>>>(
      Pb, Vt, Cx, 2048, 2048, 1024, 64,
      4194304LL, 2097152LL, 2097152LL, 1.0f);

  // 7) out = ctx @ wo^T  (M=8192, N=1024, K=1024, fp32 out)
  gemm_bt<float><<<dim3(8, 64, 1), 512, 0, stream>>>(
      Cx, wob, out, 1024, 1024, 1024, 32, 0, 0, 0, 1.0f);
}

// Round 3
// 342.872 us; speedup vs baseline: 1.2227x; 1.0990x over previous
//
#include <hip/hip_runtime.h>
#include <hip/hip_bf16.h>
#include <cstdio>
#include <cstdint>

// Attention (B=4, S=2048, D=1024, full-dim, fp32 I/O) via bf16 MFMA GEMMs.
// Round 3: 8-phase 256x256 GEMM schedule (m201 template, plain HIP):
// BK=64, 8 waves (2Mx4N, wave tile 128x64), 128 KiB LDS (2 K-tile slots),
// per phase {ds_read subtile | stage 1 half-tile | barrier | lgkmcnt(0) |
// setprio(1) 16xMFMA setprio(0) | barrier}, vmcnt(4)/vmcnt(6) at phases 4/8.

typedef __attribute__((ext_vector_type(8))) short short8;
typedef __attribute__((ext_vector_type(4))) float f32x4;

#define AS1(p) ((const __attribute__((address_space(1))) void*)(p))
#define AS3(p) ((__attribute__((address_space(3))) void*)(p))

__device__ __forceinline__ unsigned short f2bf(float f) {
  union { float f; uint32_t u; } c; c.f = f;
  uint32_t u = c.u + 0x7fffu + ((c.u >> 16) & 1u);  // RNE (no NaN inputs here)
  return (unsigned short)(u >> 16);
}

// ---------------- fp32 -> bf16 convert (float4 -> ushort4) ----------------
__global__ void cvt_f32_bf16(const float* __restrict__ in,
                             unsigned short* __restrict__ out, int n4) {
  int i = blockIdx.x * 256 + threadIdx.x;
  if (i >= n4) return;
  float4 v = ((const float4*)in)[i];
  ushort4 o;
  o.x = f2bf(v.x); o.y = f2bf(v.y); o.z = f2bf(v.z); o.w = f2bf(v.w);
  ((ushort4*)out)[i] = o;
}

// all 4 weight matrices in one launch (each 1,048,576 elems, out contiguous)
__global__ void cvt_w4(const float* __restrict__ a, const float* __restrict__ b,
                       const float* __restrict__ c, const float* __restrict__ d,
                       unsigned short* __restrict__ out) {
  const float* s = (blockIdx.y == 0) ? a : (blockIdx.y == 1) ? b
                 : (blockIdx.y == 2) ? c : d;
  int i = blockIdx.x * 256 + threadIdx.x;
  float4 v = ((const float4*)s)[i];
  ushort4 o;
  o.x = f2bf(v.x); o.y = f2bf(v.y); o.z = f2bf(v.z); o.w = f2bf(v.w);
  ((ushort4*)(out + (size_t)blockIdx.y * 1048576))[i] = o;
}

// ---------------- bf16 [2048][1024] -> [1024][2048] transpose (per batch) --
__global__ void transpose_bf16(const unsigned short* __restrict__ V,
                               unsigned short* __restrict__ Vt) {
  __shared__ unsigned short tile[64][72];
  const int b = blockIdx.z;
  const unsigned short* v = V + (size_t)b * 2048 * 1024;
  unsigned short* vt = Vt + (size_t)b * 1024 * 2048;
  const int d0 = blockIdx.x * 64, s0 = blockIdx.y * 64;
  const int t = threadIdx.x;
#pragma unroll
  for (int it = 0; it < 16; ++it) {
    int idx = it * 256 + t, r = idx >> 6, c = idx & 63;
    tile[r][c] = v[(size_t)(s0 + r) * 1024 + d0 + c];
  }
  __syncthreads();
#pragma unroll
  for (int it = 0; it < 16; ++it) {
    int idx = it * 256 + t, r = idx >> 6, c = idx & 63;
    vt[(size_t)(d0 + r) * 2048 + s0 + c] = tile[c][r];
  }
}

// ---------------- row softmax: fp32 [rows][2048] -> bf16 P -----------------
__global__ void softmax_rows(const float* __restrict__ S,
                             unsigned short* __restrict__ P) {
  const size_t row = blockIdx.x;
  const float* s = S + row * 2048;
  const int t = threadIdx.x, l = t & 63, w = t >> 6;
  float4 v0 = ((const float4*)s)[t * 2];
  float4 v1 = ((const float4*)s)[t * 2 + 1];
  float x[8] = {v0.x, v0.y, v0.z, v0.w, v1.x, v1.y, v1.z, v1.w};
  float m = x[0];
#pragma unroll
  for (int j = 1; j < 8; ++j) m = fmaxf(m, x[j]);
#pragma unroll
  for (int d = 32; d; d >>= 1) m = fmaxf(m, __shfl_xor(m, d));
  __shared__ float rm[4], rs[4];
  if (l == 0) rm[w] = m;
  __syncthreads();
  m = fmaxf(fmaxf(rm[0], rm[1]), fmaxf(rm[2], rm[3]));
  float e[8], sum = 0.f;
#pragma unroll
  for (int j = 0; j < 8; ++j) { e[j] = __expf(x[j] - m); sum += e[j]; }
#pragma unroll
  for (int d = 32; d; d >>= 1) sum += __shfl_xor(sum, d);
  if (l == 0) rs[w] = sum;
  __syncthreads();
  float inv = 1.0f / (rs[0] + rs[1] + rs[2] + rs[3]);
  short8 o;
#pragma unroll
  for (int j = 0; j < 8; ++j) o[j] = (short)f2bf(e[j] * inv);
  *(short8*)(P + row * 2048 + t * 8) = o;
}

// ---------------- 8-phase 256x256 bf16 GEMM, C = scale * A @ B^T -----------
// LDS map (bytes): slot s in {0,1} at s*65536; A at +0 (h0 @0, h1 @16384),
// B at +32768 (h0 @32768, h1 @49152). Each half = 16 chunks of 1 KB;
// chunk (fr,kk) at (fr*2+kk)*1024, lane l's 16B at +l*16 holds
// M[base + fr*16 + (l&15)][t*64 + kk*32 + (l>>4)*8 ..+8]  (fragment-linear,
// conflict-free ds_read_b128, stage permutation on the global src address).
// Stage ownership: wave w stages chunk fr=w, kk=j (2 loads/half-tile/thread).
// Stage schedule per iter i (tiles t0=2i, t0+1): ph1:A(t0+1)h1, ph3:B(t0+2)h0,
// ph4:B(t0+2)h1, ph5:A(t0+2)h0, ph6:A(t0+2)h1, ph7:B(t0+3)h0,
// ph8:B(t0+3)h1+A(t0+3)h0.  vmcnt(4)@ph4, vmcnt(6)@ph8 (counted, never 0
// in steady state).  Every stage is >=1 full barrier after the last read of
// the LDS region it overwrites (A halves last read ph3/ph7, B halves ph2/ph6).
__device__ __forceinline__ void store_out(float* p, float v) { *p = v; }
__device__ __forceinline__ void store_out(unsigned short* p, float v) { *p = f2bf(v); }

template <typename OutT>
__global__ __launch_bounds__(512, 2) void gemm8p(
    const unsigned short* __restrict__ A, const unsigned short* __restrict__ B,
    OutT* __restrict__ C, int lda, int ldb, int ldc, int nT,  // nT = K/64
    long long aStride, long long bStride, long long cStride, float scale) {
  __shared__ unsigned short lds[65536];  // 128 KiB
  const int l = threadIdx.x & 63, w = threadIdx.x >> 6;
  const int wr = w >> 2, wc = w & 3;  // 2M x 4N waves, wave tile 128x64

  // bijective XCD-aware block swizzle (all grids here have nwg % 8 == 0)
  const int gx = gridDim.x, gy = gridDim.y;
  int f = blockIdx.x + gx * (blockIdx.y + gy * blockIdx.z);
  int nwg = gx * gy * gridDim.z;
  int work = ((nwg & 7) == 0) ? ((f & 7) * (nwg >> 3) + (f >> 3)) : f;
  const int bx = work % gx;
  int rem = work / gx;
  const int by = rem % gy, bz = rem / gy;
  const long long r0 = (long long)by * 256, c0 = (long long)bx * 256;
  A += (size_t)bz * aStride;
  B += (size_t)bz * bStride;
  C += (size_t)bz * cStride;

  const unsigned short* aS = A + (size_t)(r0 + w * 16 + (l & 15)) * lda + (l >> 4) * 8;
  const unsigned short* bS = B + (size_t)(c0 + w * 16 + (l & 15)) * ldb + (l >> 4) * 8;
  const size_t a128 = (size_t)128 * lda, b128 = (size_t)128 * ldb;
  char* const ldsc = (char*)lds;
  const int dstW = (w * 2) << 10;

#define STAGE_A(t_, h_)                                                        \
  do {                                                                         \
    const unsigned short* s_ = aS + ((h_) ? a128 : 0) + (t_) * 64;             \
    char* d_ = ldsc + (((t_) & 1) << 16) + ((h_) << 14) + dstW;                \
    __builtin_amdgcn_global_load_lds(AS1(s_), AS3(d_), 16, 0, 0);              \
    __builtin_amdgcn_global_load_lds(AS1(s_ + 32), AS3(d_ + 1024), 16, 0, 0);  \
  } while (0)
#define STAGE_B(t_, h_)                                                        \
  do {                                                                         \
    const unsigned short* s_ = bS + ((h_) ? b128 : 0) + (t_) * 64;             \
    char* d_ = ldsc + (((t_) & 1) << 16) + 32768 + ((h_) << 14) + dstW;        \
    __builtin_amdgcn_global_load_lds(AS1(s_), AS3(d_), 16, 0, 0);              \
    __builtin_amdgcn_global_load_lds(AS1(s_ + 32), AS3(d_ + 1024), 16, 0, 0);  \
  } while (0)

  short8 a[8], b0[4], b1[4];
  f32x4 acc[8][4] = {};

  const int aBase = wr << 14;                  // this wave's A half
  const int bBase = 32768 + ((wc >> 1) << 14); // this wave's B half
  const int bFr = (wc & 1) * 4;                // first B frag in that half
  const int loff = l * 16;

#define LDA_SET(s_, qm_)                                                       \
  _Pragma("unroll") for (int m2 = 0; m2 < 4; ++m2)                             \
  _Pragma("unroll") for (int kk = 0; kk < 2; ++kk)                             \
      a[m2 * 2 + kk] = *(const short8*)(ldsc + ((s_) << 16) + aBase +          \
                                        ((((qm_) * 4 + m2) * 2 + kk) << 10) + loff);
#define LDB_SET(s_, qn_, dst_)                                                 \
  _Pragma("unroll") for (int n2 = 0; n2 < 2; ++n2)                             \
  _Pragma("unroll") for (int kk = 0; kk < 2; ++kk)                             \
      dst_[n2 * 2 + kk] = *(const short8*)(ldsc + ((s_) << 16) + bBase +       \
                                           (((bFr + (qn_) * 2 + n2) * 2 + kk) << 10) + loff);
#define MFMA_Q(qm_, qn_, bset_)                                                \
  __builtin_amdgcn_s_setprio(1);                                               \
  _Pragma("unroll") for (int m2 = 0; m2 < 4; ++m2)                             \
  _Pragma("unroll") for (int n2 = 0; n2 < 2; ++n2)                             \
  _Pragma("unroll") for (int kk = 0; kk < 2; ++kk)                             \
      acc[(qm_) * 4 + m2][(qn_) * 2 + n2] =                                    \
          __builtin_amdgcn_mfma_f32_16x16x32_bf16(                             \
              a[m2 * 2 + kk], bset_[n2 * 2 + kk],                              \
              acc[(qm_) * 4 + m2][(qn_) * 2 + n2], 0, 0, 0);                   \
  __builtin_amdgcn_s_setprio(0);
#define BAR() asm volatile("s_barrier" ::: "memory")
#define LGKM0() asm volatile("s_waitcnt lgkmcnt(0)" ::: "memory")
#define VMC(n_) asm volatile("s_waitcnt vmcnt(" #n_ ")" ::: "memory")

  // prologue: 7 half-tiles; vmcnt(6) completes all of tile 0
  STAGE_B(0, 0); STAGE_B(0, 1); STAGE_A(0, 0); STAGE_A(0, 1);
  STAGE_B(1, 0); STAGE_B(1, 1); STAGE_A(1, 0);
  VMC(6); BAR();

  const int nI = nT >> 1;
  for (int i = 0; i < nI; ++i) {
    const int t0 = 2 * i;
    const bool last = (i == nI - 1);
    // ph1: tile t0, Q(0,0)
    LDA_SET(0, 0); LDB_SET(0, 0, b0);
    STAGE_A(t0 + 1, 1);
    BAR(); LGKM0(); MFMA_Q(0, 0, b0); BAR();
    // ph2: Q(0,1)
    LDB_SET(0, 1, b1);
    BAR(); LGKM0(); MFMA_Q(0, 1, b1); BAR();
    // ph3: Q(1,1)
    LDA_SET(0, 1);
    if (!last) STAGE_B(t0 + 2, 0);
    BAR(); LGKM0(); MFMA_Q(1, 1, b1); BAR();
    // ph4: Q(1,0)  — drain so all of tile t0+1 is resident
    if (!last) { STAGE_B(t0 + 2, 1); VMC(4); } else { VMC(0); }
    BAR(); MFMA_Q(1, 0, b0); BAR();
    // ph5: tile t0+1, Q(0,0)
    LDA_SET(1, 0); LDB_SET(1, 0, b0);
    if (!last) STAGE_A(t0 + 2, 0);
    BAR(); LGKM0(); MFMA_Q(0, 0, b0); BAR();
    // ph6: Q(0,1)
    LDB_SET(1, 1, b1);
    if (!last) STAGE_A(t0 + 2, 1);
    BAR(); LGKM0(); MFMA_Q(0, 1, b1); BAR();
    // ph7: Q(1,1)
    LDA_SET(1, 1);
    if (!last) STAGE_B(t0 + 3, 0);
    BAR(); LGKM0(); MFMA_Q(1, 1, b1); BAR();
    // ph8: Q(1,0) — drain so all of tile t0+2 is resident
    if (!last) { STAGE_B(t0 + 3, 1); STAGE_A(t0 + 3, 0); VMC(6); }
    BAR(); MFMA_Q(1, 0, b0); BAR();
  }
#undef STAGE_A
#undef STAGE_B
#undef LDA_SET
#undef LDB_SET
#undef MFMA_Q

  // C-write. C/D layout (round-1 verified): col = lane&15, row = (lane>>4)*4+i
  const int cr = (l >> 4) * 4, cc = l & 15;
  const long long rowb = r0 + wr * 128, colb = c0 + wc * 64;
#pragma unroll
  for (int m = 0; m < 8; ++m)
#pragma unroll
    for (int n = 0; n < 4; ++n) {
      long long col = colb + n * 16 + cc;
#pragma unroll
      for (int i2 = 0; i2 < 4; ++i2) {
        long long row = rowb + m * 16 + cr + i2;
        store_out(&C[row * ldc + col], acc[m][n][i2] * scale);
      }
    }
}

// ---------------- workspace layout (bytes, all 256-aligned) ----------------
static const size_t OFF_XB  = 0;            // x bf16        16,777,216
static const size_t OFF_WQ  = 16777216;     // wq bf16        2,097,152
static const size_t OFF_WK  = 18874368;
static const size_t OFF_WV  = 20971520;
static const size_t OFF_WO  = 23068672;
static const size_t OFF_Q   = 25165824;     // Q bf16        16,777,216
static const size_t OFF_K   = 41943040;
static const size_t OFF_V   = 58720256;
static const size_t OFF_VT  = 75497472;     // V^T bf16      16,777,216
static const size_t OFF_SC  = 92274688;     // scores fp32   67,108,864
static const size_t OFF_P   = 159383552;    // P bf16        33,554,432
static const size_t OFF_CTX = 192937984;    // ctx bf16      16,777,216
static const size_t WS_NEED = 209715200;    // 200 MiB

extern "C" void kernel_launch(void* const* d_in, const int* in_sizes, int n_in,
                              void* d_out, int out_size, void* d_ws, size_t ws_size,
                              hipStream_t stream) {
  const float* x  = (const float*)d_in[0];
  const float* wq = (const float*)d_in[1];
  const float* wk = (const float*)d_in[2];
  const float* wv = (const float*)d_in[3];
  const float* wo = (const float*)d_in[4];
  float* out = (float*)d_out;

  if (ws_size < WS_NEED) {
    fprintf(stderr, "kernel_launch: ws_size=%zu < needed %zu\n", ws_size, WS_NEED);
    return;
  }
  char* ws = (char*)d_ws;
  unsigned short* xb  = (unsigned short*)(ws + OFF_XB);
  unsigned short* wqb = (unsigned short*)(ws + OFF_WQ);
  unsigned short* wob = (unsigned short*)(ws + OFF_WO);
  unsigned short* Qb  = (unsigned short*)(ws + OFF_Q);
  unsigned short* Kb  = (unsigned short*)(ws + OFF_K);
  unsigned short* Vb  = (unsigned short*)(ws + OFF_V);
  unsigned short* Vt  = (unsigned short*)(ws + OFF_VT);
  float*          Sc  = (float*)(ws + OFF_SC);
  unsigned short* Pb  = (unsigned short*)(ws + OFF_P);
  unsigned short* Cx  = (unsigned short*)(ws + OFF_CTX);

  // 1) convert inputs to bf16 (weights land contiguous at OFF_WQ..OFF_WO)
  cvt_f32_bf16<<<8192, 256, 0, stream>>>(x, xb, 2097152);
  cvt_w4<<<dim3(1024, 4, 1), 256, 0, stream>>>(wq, wk, wv, wo, wqb);

  // 2) fused QKV: z selects weight (bStride) and output (cStride)
  //    M=8192, N=1024, K=1024 per z; 384 blocks
  gemm8p<unsigned short><<<dim3(4, 32, 3), 512, 0, stream>>>(
      xb, wqb, Qb, 1024, 1024, 1024, 16, 0, 1048576LL, 8388608LL, 1.0f);

  // 3) V^T per batch
  transpose_bf16<<<dim3(16, 32, 4), 256, 0, stream>>>(Vb, Vt);

  // 4) scores = Q @ K^T / 32  (per batch, M=N=2048, K=1024, fp32 out); 256 blocks
  gemm8p<float><<<dim3(8, 8, 4), 512, 0, stream>>>(
      Qb, Kb, Sc, 1024, 1024, 2048, 16,
      2097152LL, 2097152LL, 4194304LL, 0.03125f);

  // 5) P = softmax(scores) -> bf16
  softmax_rows<<<8192, 256, 0, stream>>>(Sc, Pb);

  // 6) ctx = P @ V  (per batch, M=2048, N=1024, K=2048); 128 blocks
  gemm8p<unsigned short><<<dim3(4, 8, 4), 512, 0, stream>>>(
      Pb, Vt, Cx, 2048, 2048, 1024, 32,
      4194304LL, 2097152LL, 2097152LL, 1.0f);

  // 7) out = ctx @ wo^T  (M=8192, N=1024, K=1024); 128 blocks
  gemm8p<float><<<dim3(4, 32, 1), 512, 0, stream>>>(
      Cx, wob, out, 1024, 1024, 1024, 16, 0, 0, 0, 1.0f);
}